// Round 13
// baseline (398.335 us; speedup 1.0000x reference)
//
#include <hip/hip_runtime.h>
#include <hip/hip_bf16.h>
#include <math.h>

#define T_TOK   131072
#define D_IN    2048
#define H_CH    260
#define NFRAG   17           // 17*16 = 272 padded N
#define KSTEPS  64           // 2048/32
#define STEP_BYTES  (NFRAG * 64 * 16)     // 17408 B per K-step of Wfrag
#define CHUNK_BYTES (2 * STEP_BYTES)      // 34816 B (2 K-steps)
#define NCHUNK  32

typedef __attribute__((ext_vector_type(8))) short bf16x8;
typedef __attribute__((ext_vector_type(4))) float f32x4;

__device__ inline short f2bf(float x) {
    __hip_bfloat16 h = __float2bfloat16(x);
    return __builtin_bit_cast(short, h);
}

// ---------------------------------------------------------------------------
// Prep: pack W_down [2048,260] fp32 -> MFMA-fragment-ready bf16 layout
// ---------------------------------------------------------------------------
__global__ void prep_wfrag(const float* __restrict__ W, __hip_bfloat16* __restrict__ Wf) {
    int g = blockIdx.x;                 // 0 .. KSTEPS*NFRAG-1
    int s = g / NFRAG, f = g % NFRAG;
    int lane = threadIdx.x;
    int k0 = s * 32 + (lane >> 4) * 8;
    int col = f * 16 + (lane & 15);
    short vals8[8];
#pragma unroll
    for (int j = 0; j < 8; j++) {
        float v = (col < H_CH) ? W[(size_t)(k0 + j) * H_CH + col] : 0.f;
        vals8[j] = f2bf(v);
    }
    *reinterpret_cast<bf16x8*>(reinterpret_cast<short*>(Wf) + ((size_t)g * 64 + lane) * 8) =
        *reinterpret_cast<bf16x8*>(vals8);
}

// ---------------------------------------------------------------------------
// Main GEMM (exact R5 structure). Block = 512 threads (8 waves), M=128 rows
// -> 16 rows/wave, full N=272. acc = 17 f32x4 = 68 VGPR -> 4 waves/SIMD.
// Epilogue now emits ONLY per-token compact features:
//   attnL[T,4] fp32 (raw attention logits), uvals[T,4] fp32 (per-head
//   GELU-value dot with W_final), token_logits[T].
// The 67 MB bf16 vals tensor is eliminated entirely.
// ---------------------------------------------------------------------------
__global__ __launch_bounds__(512, 4)
void gemm_act(const float* __restrict__ emb, const __hip_bfloat16* __restrict__ Wfrag,
              const float* __restrict__ b_down, const float* __restrict__ W_final,
              const float* __restrict__ b_final,
              float* __restrict__ attnL, float* __restrict__ uvals,
              float* __restrict__ token_logits) {
    __shared__ __align__(16) char smem[2 * CHUNK_BYTES];   // 68 KB

    int wave = threadIdx.x >> 6;
    int lane = threadIdx.x & 63;
    int r0 = blockIdx.x * 128 + wave * 16;
    int row_in = lane & 15;
    int kbase = (lane >> 4) * 8;

    const char* gW = (const char*)Wfrag;

    // 34 x 1024B per chunk; waves 0..1 take a 5th segment.
    auto stage_chunk = [&](int c, char* lbase) {
        const char* src = gW + (size_t)c * CHUNK_BYTES;
#pragma unroll
        for (int r = 0; r < 4; ++r) {
            int off = (r * 8 + wave) * 1024;
            __builtin_amdgcn_global_load_lds(
                (const __attribute__((address_space(1))) unsigned int*)(src + off + lane * 16),
                (__attribute__((address_space(3))) unsigned int*)(lbase + off), 16, 0, 0);
        }
        if (wave < 2) {
            int off = (32 + wave) * 1024;
            __builtin_amdgcn_global_load_lds(
                (const __attribute__((address_space(1))) unsigned int*)(src + off + lane * 16),
                (__attribute__((address_space(3))) unsigned int*)(lbase + off), 16, 0, 0);
        }
    };

    f32x4 acc[NFRAG];
#pragma unroll
    for (int f = 0; f < NFRAG; f++) acc[f] = (f32x4){0.f, 0.f, 0.f, 0.f};

    const float* aptr = emb + (size_t)(r0 + row_in) * D_IN + kbase;

    // prologue
    stage_chunk(0, smem);
    f32x4 cl = *reinterpret_cast<const f32x4*>(aptr);
    f32x4 ch = *reinterpret_cast<const f32x4*>(aptr + 4);
    f32x4 nl, nh;
    __syncthreads();   // chunk 0 resident

#define DO_STEP(AL, AH, BOFF)                                                     \
    {                                                                             \
        bf16x8 af;                                                                \
        af[0] = f2bf(AL[0]); af[1] = f2bf(AL[1]);                                 \
        af[2] = f2bf(AL[2]); af[3] = f2bf(AL[3]);                                 \
        af[4] = f2bf(AH[0]); af[5] = f2bf(AH[1]);                                 \
        af[6] = f2bf(AH[2]); af[7] = f2bf(AH[3]);                                 \
        const char* bb = smem + (BOFF) + lane * 16;                               \
        _Pragma("unroll")                                                         \
        for (int f = 0; f < NFRAG; f++) {                                         \
            bf16x8 bfr = *reinterpret_cast<const bf16x8*>(bb + f * 1024);         \
            acc[f] = __builtin_amdgcn_mfma_f32_16x16x32_bf16(af, bfr, acc[f], 0, 0, 0); \
        }                                                                         \
    }

    for (int c = 0; c < NCHUNK; ++c) {
        int base = (c & 1) * CHUNK_BYTES;
        if (c + 1 < NCHUNK) stage_chunk(c + 1, smem + ((c + 1) & 1) * CHUNK_BYTES);

        // step 2c: prefetch A(2c+1), compute
        int off1 = (2 * c + 1) * 32;
        nl = *reinterpret_cast<const f32x4*>(aptr + off1);
        nh = *reinterpret_cast<const f32x4*>(aptr + off1 + 4);
        DO_STEP(cl, ch, base)

        // step 2c+1: prefetch A(2c+2), compute
        int s2 = 2 * c + 2;
        int off2 = (s2 < KSTEPS ? s2 : 0) * 32;
        cl = *reinterpret_cast<const f32x4*>(aptr + off2);
        ch = *reinterpret_cast<const f32x4*>(aptr + off2 + 4);
        DO_STEP(nl, nh, base + STEP_BYTES)

        __syncthreads();   // next chunk resident; buf[c&1] free
    }
#undef DO_STEP

    // Epilogue: bias + GELU, per-head W_final dot -> u[row][h], attnL, token logit.
    int colbase = lane & 15;
    int rgroup = (lane >> 4) * 4;
    float tph[4][4];   // [i][head], static indexing only
#pragma unroll
    for (int i = 0; i < 4; i++)
#pragma unroll
        for (int h = 0; h < 4; h++) tph[i][h] = 0.f;

#pragma unroll
    for (int f = 0; f < NFRAG; f++) {
        int n = f * 16 + colbase;
        float bias = (n < H_CH) ? b_down[n] : 0.f;
        float wf = (n >= 4 && n < H_CH) ? W_final[n - 4] : 0.f;
        int hidx = (n >= 4) ? ((n - 4) >> 6) : 0;   // head of this column
#pragma unroll
        for (int i = 0; i < 4; i++) {
            int row = r0 + rgroup + i;
            float v = acc[f][i] + bias;
            float a = (n < 4) ? v : 0.5f * v * (1.f + erff(v * 0.70710678118f));
            if (n < 4) attnL[(size_t)row * 4 + n] = v;
            float contrib = a * wf;   // 0 for n<4 and n>=260
            tph[i][0] += (hidx == 0) ? contrib : 0.f;
            tph[i][1] += (hidx == 1) ? contrib : 0.f;
            tph[i][2] += (hidx == 2) ? contrib : 0.f;
            tph[i][3] += (hidx == 3) ? contrib : 0.f;
        }
    }
    // reduce each of the 16 partials across the 16-lane row group
#pragma unroll
    for (int i = 0; i < 4; i++)
#pragma unroll
        for (int h = 0; h < 4; h++) {
            float v = tph[i][h];
            v += __shfl_xor(v, 1);
            v += __shfl_xor(v, 2);
            v += __shfl_xor(v, 4);
            v += __shfl_xor(v, 8);
            tph[i][h] = v;
        }
    if ((lane & 15) == 0) {
#pragma unroll
        for (int i = 0; i < 4; i++) {
            int row = r0 + rgroup + i;
            f32x4 u = (f32x4){tph[i][0], tph[i][1], tph[i][2], tph[i][3]};
            *reinterpret_cast<f32x4*>(uvals + (size_t)row * 4) = u;
            token_logits[row] = u[0] + u[1] + u[2] + u[3] + b_final[0];
        }
    }
}

// ---------------------------------------------------------------------------
// Problem pooling over compact features: 256 blocks x 256 threads.
// Reads attnL/uvals [512,4] per problem (16 KB) — trivial traffic.
// ---------------------------------------------------------------------------
__global__ __launch_bounds__(256)
void pool_problem(const float* __restrict__ attnL, const float* __restrict__ uvals,
                  const int* __restrict__ labels, const float* __restrict__ b_final,
                  float* __restrict__ out_logits, float* __restrict__ out_labels) {
    __shared__ float mred[4][4];
    __shared__ float nred[4][4];
    __shared__ float dred[4][4];
    __shared__ int   lred[4];

    int p = blockIdx.x;
    int t = threadIdx.x;
    int lane = t & 63, wid = t >> 6;
    const float* ab = attnL + (size_t)p * 2048;
    const float* ub = uvals + (size_t)p * 2048;

    f32x4 x0 = *reinterpret_cast<const f32x4*>(ab + (size_t)t * 4);
    f32x4 x1 = *reinterpret_cast<const f32x4*>(ab + (size_t)(t + 256) * 4);
    f32x4 q0 = *reinterpret_cast<const f32x4*>(ub + (size_t)t * 4);
    f32x4 q1 = *reinterpret_cast<const f32x4*>(ub + (size_t)(t + 256) * 4);

    float mh[4];
#pragma unroll
    for (int h = 0; h < 4; h++) mh[h] = fmaxf(x0[h], x1[h]);
#pragma unroll
    for (int h = 0; h < 4; h++)
        for (int mask = 1; mask < 64; mask <<= 1) mh[h] = fmaxf(mh[h], __shfl_xor(mh[h], mask));
    if (lane == 0) {
#pragma unroll
        for (int h = 0; h < 4; h++) mred[wid][h] = mh[h];
    }
    __syncthreads();
#pragma unroll
    for (int h = 0; h < 4; h++)
        mh[h] = fmaxf(fmaxf(mred[0][h], mred[1][h]), fmaxf(mred[2][h], mred[3][h]));

    float nh[4], dh[4];
#pragma unroll
    for (int h = 0; h < 4; h++) {
        float e0 = __expf(x0[h] - mh[h]);
        float e1 = __expf(x1[h] - mh[h]);
        dh[h] = e0 + e1;
        nh[h] = e0 * q0[h] + e1 * q1[h];
    }
#pragma unroll
    for (int h = 0; h < 4; h++)
        for (int mask = 1; mask < 64; mask <<= 1) {
            nh[h] += __shfl_xor(nh[h], mask);
            dh[h] += __shfl_xor(dh[h], mask);
        }
    if (lane == 0) {
#pragma unroll
        for (int h = 0; h < 4; h++) { nred[wid][h] = nh[h]; dred[wid][h] = dh[h]; }
    }

    int lmin = min(labels[p * 512 + t], labels[p * 512 + t + 256]);
    for (int mask = 1; mask < 64; mask <<= 1) lmin = min(lmin, __shfl_xor(lmin, mask));
    if (lane == 0) lred[wid] = lmin;
    __syncthreads();
    if (t == 0) {
        float logit = b_final[0];
#pragma unroll
        for (int h = 0; h < 4; h++) {
            float num = nred[0][h] + nred[1][h] + nred[2][h] + nred[3][h];
            float den = dred[0][h] + dred[1][h] + dred[2][h] + dred[3][h];
            logit += num / den;
        }
        out_logits[p] = logit;
        out_labels[p] = (float)min(min(lred[0], lred[1]), min(lred[2], lred[3]));
    }
}

// ---------------------------------------------------------------------------
// Line pooling over compact features: one wave per line. Grid 2048 x 256.
// lane = s*4 + h over the 16-token line.
// ---------------------------------------------------------------------------
__global__ __launch_bounds__(256)
void pool_line(const float* __restrict__ attnL, const float* __restrict__ uvals,
               const int* __restrict__ labels, const float* __restrict__ b_final,
               float* __restrict__ out_logits, float* __restrict__ out_labels) {
    int wid = threadIdx.x >> 6, lane = threadIdx.x & 63;
    int line = blockIdx.x * 4 + wid;

    float x = attnL[(size_t)line * 64 + lane];
    float u = uvals[(size_t)line * 64 + lane];

    float mm = x;
    mm = fmaxf(mm, __shfl_xor(mm, 4));
    mm = fmaxf(mm, __shfl_xor(mm, 8));
    mm = fmaxf(mm, __shfl_xor(mm, 16));
    mm = fmaxf(mm, __shfl_xor(mm, 32));
    float e = __expf(x - mm);
    float Z = e;
    Z += __shfl_xor(Z, 4);
    Z += __shfl_xor(Z, 8);
    Z += __shfl_xor(Z, 16);
    Z += __shfl_xor(Z, 32);
    float part = (e / Z) * u;

    for (int mask = 1; mask < 64; mask <<= 1) part += __shfl_xor(part, mask);

    int lab = (lane < 16) ? labels[line * 16 + lane] : 0x7fffffff;
    for (int mask = 1; mask < 64; mask <<= 1) lab = min(lab, __shfl_xor(lab, mask));

    if (lane == 0) {
        out_logits[line] = part + b_final[0];
        out_labels[line] = (float)lab;
    }
}

// ---------------------------------------------------------------------------
extern "C" void kernel_launch(void* const* d_in, const int* in_sizes, int n_in,
                              void* d_out, int out_size, void* d_ws, size_t ws_size,
                              hipStream_t stream) {
    const float* emb     = (const float*)d_in[0];
    const float* W_down  = (const float*)d_in[1];
    const float* b_down  = (const float*)d_in[2];
    const float* W_final = (const float*)d_in[3];
    const float* b_final = (const float*)d_in[4];
    const int*   labels  = (const int*)d_in[5];

    float* out      = (float*)d_out;
    float* tok      = out;               // [131072]
    float* line_lg  = out + 131072;      // [8192]
    float* line_lb  = out + 139264;      // [8192]
    float* prob_lg  = out + 147456;      // [256]
    float* prob_lb  = out + 147712;      // [256]

    __hip_bfloat16* Wfrag = (__hip_bfloat16*)d_ws;                     // 1.1 MB
    float* attnL = (float*)((char*)d_ws + ((size_t)4 << 20));          // 2.1 MB
    float* uvals = (float*)((char*)d_ws + ((size_t)8 << 20));          // 2.1 MB

    prep_wfrag<<<KSTEPS * NFRAG, 64, 0, stream>>>(W_down, Wfrag);
    gemm_act<<<T_TOK / 128, 512, 0, stream>>>(emb, Wfrag, b_down, W_final, b_final,
                                              attnL, uvals, tok);
    pool_problem<<<256, 256, 0, stream>>>(attnL, uvals, labels, b_final, prob_lg, prob_lb);
    pool_line<<<2048, 256, 0, stream>>>(attnL, uvals, labels, b_final, line_lg, line_lb);
}